// Round 2
// baseline (2448.811 us; speedup 1.0000x reference)
//
#include <hip/hip_runtime.h>
#include <hip/hip_bf16.h>
#include <cstdint>

typedef __hip_bfloat16 bf16;
typedef unsigned int u32;

#define S_SRC 512
#define E_DIM 128
#define NSTEP 63
#define VOUT_N 32000

__device__ __forceinline__ float b2f(bf16 x) { return __bfloat162float(x); }

// read element i of a raw float input, dtype per flag (1 = bf16, 0 = fp32)
__device__ __forceinline__ float rdw(const void* p, size_t i, int isbf) {
  return isbf ? __bfloat162float(((const bf16*)p)[i]) : ((const float*)p)[i];
}

// ---------------- dtype detect ----------------
// If the data is fp32, the low 16 bits of each 32-bit word are mantissa noise
// whose bf16 decode has a random exponent -> some |x| >> 4 among 960 words.
// True bf16 N(0,0.02) data decodes to |x| <= ~0.2 everywhere.
__global__ void detect_kernel(const void* emb, int* flag) {
  const u32* w = (const u32*)emb;
  int bad = 0;
  for (int i = 64 + (int)threadIdx.x; i < 64 + 1024; i += 64) {
    float f = __uint_as_float(w[i] << 16);
    if (!(fabsf(f) <= 4.0f)) bad = 1;   // catches huge + NaN
  }
  unsigned long long m = __ballot(bad);
  if (threadIdx.x == 0) flag[0] = (m == 0ull) ? 1 : 0;  // 1 = bf16 data
}

// ---------------- w_hh -> fp32 scratch ----------------
__global__ void cvt_whh_kernel(const void* w, const int* __restrict__ flag,
                               float* __restrict__ dst) {
  int i = blockIdx.x * 256 + threadIdx.x;  // 65536
  dst[i] = rdw(w, i, flag[0]);
}

// ---------------- embedding gathers ----------------
__global__ void embed_src_kernel(const int* __restrict__ src, const void* __restrict__ emb,
                                 const int* __restrict__ flag, float* __restrict__ X) {
  const int isbf = flag[0];
  int idx = blockIdx.x * 256 + threadIdx.x;  // 32768*128
  int row = idx >> 7, e = idx & 127;
  X[idx] = rdw(emb, (size_t)src[row] * E_DIM + e, isbf);
}

__global__ void embed_trg_kernel(const int* __restrict__ trg, const void* __restrict__ emb,
                                 const int* __restrict__ flag, float* __restrict__ D) {
  const int isbf = flag[0];
  int idx = blockIdx.x * 256 + threadIdx.x;  // 4032*128, row = t*64+b
  int row = idx >> 7, e = idx & 127;
  int t = row >> 6, b = row & 63;
  int tok = trg[b * 64 + t];                 // trg is [64,64]
  D[idx] = rdw(emb, (size_t)tok * E_DIM + e, isbf);
}

// ---------------- generic GEMM: C[M,N] = A[M,K] * B[N,K]^T (+bias) ----------------
// Bw/bias/bias2 are raw inputs (dtype per flag) with explicit ELEMENT offsets.
// MODE 0: +bias -> f32 | 1: relu(+bias) -> f32 | 2: +bias+bias2 -> f32
// MODE 4: +bias -> (bf16|f32 per flag) with row remap r=t*64+b -> out[(b*63+t)*32000+n]
template<int MODE>
__global__ __launch_bounds__(256)
void gemm_kernel(const float* __restrict__ A, const void* __restrict__ Bw, size_t b_off,
                 const void* __restrict__ bias, size_t bi_off,
                 const void* __restrict__ bias2,
                 const int* __restrict__ flag,
                 float* __restrict__ C, void* __restrict__ Cout,
                 int M, int N, int K) {
  __shared__ float As[16][68];
  __shared__ float Bs[16][68];
  const int isbf = flag[0];
  const int tid = threadIdx.x;
  const int m0 = blockIdx.x * 64, n0 = blockIdx.y * 64;
  const int kk = tid & 15, mm = tid >> 4;
  const int tx = tid & 15, ty = tid >> 4;
  float acc[4][4] = {};
  for (int k0 = 0; k0 < K; k0 += 16) {
#pragma unroll
    for (int r = 0; r < 4; r++) {
      As[kk][mm + r * 16] = A[(size_t)(m0 + mm + r * 16) * K + k0 + kk];
      Bs[kk][mm + r * 16] = rdw(Bw, b_off + (size_t)(n0 + mm + r * 16) * K + k0 + kk, isbf);
    }
    __syncthreads();
#pragma unroll
    for (int k2 = 0; k2 < 16; k2++) {
      float4 a = *(const float4*)&As[k2][ty * 4];
      float4 b = *(const float4*)&Bs[k2][tx * 4];
      float av[4] = {a.x, a.y, a.z, a.w};
      float bv[4] = {b.x, b.y, b.z, b.w};
#pragma unroll
      for (int i = 0; i < 4; i++)
#pragma unroll
        for (int j = 0; j < 4; j++) acc[i][j] += av[i] * bv[j];
    }
    __syncthreads();
  }
  float bsv[4];
#pragma unroll
  for (int j = 0; j < 4; j++) {
    bsv[j] = rdw(bias, bi_off + n0 + tx * 4 + j, isbf);
    if (MODE == 2) bsv[j] += rdw(bias2, (size_t)(n0 + tx * 4 + j), isbf);
  }
#pragma unroll
  for (int i = 0; i < 4; i++) {
    int row = m0 + ty * 4 + i;
#pragma unroll
    for (int j = 0; j < 4; j++) {
      float v = acc[i][j] + bsv[j];
      if (MODE == 1) v = fmaxf(v, 0.f);
      if (MODE == 4) {
        int t = row >> 6, b = row & 63;
        size_t oi = (size_t)(b * NSTEP + t) * VOUT_N + n0 + tx * 4 + j;
        if (isbf) ((bf16*)Cout)[oi] = __float2bfloat16(v);
        else      ((float*)Cout)[oi] = v;
      } else {
        C[(size_t)row * N + n0 + tx * 4 + j] = v;
      }
    }
  }
}

// ---------------- fused attention: one block per (b,h), K/V in LDS ----------------
__global__ __launch_bounds__(256)
void attn_kernel(const float* __restrict__ qkv, float* __restrict__ ctx) {
  extern __shared__ float smem[];
  float* KT = smem;             // [32][512]
  float* Vs = smem + 16384;     // [512][32]
  float* ps = smem + 32768;     // [4 waves][512 float2]
  int bh = blockIdx.x;
  int b = bh >> 2, h = bh & 3;
  int tid = threadIdx.x;
  for (int idx = tid; idx < 512 * 32; idx += 256) {
    int s = idx >> 5, d = idx & 31;
    size_t base = ((size_t)(b * 512 + s)) * 384 + h * 32 + d;
    KT[d * 512 + s] = qkv[base + 128];
    Vs[idx] = qkv[base + 256];
  }
  __syncthreads();
  int wave = tid >> 6, lane = tid & 63;
  float2* pw = (float2*)(ps + wave * 1024);
  const float scale = 0.17677669529663687f;  // 1/sqrt(32)
  for (int q0 = wave * 2; q0 < 512; q0 += 8) {
    const float4* qp0 = (const float4*)(qkv + ((size_t)(b * 512 + q0)) * 384 + h * 32);
    const float4* qp1 = (const float4*)(qkv + ((size_t)(b * 512 + q0 + 1)) * 384 + h * 32);
    float qa[32], qb[32];
#pragma unroll
    for (int i = 0; i < 8; i++) {
      float4 t0 = qp0[i]; float4 t1 = qp1[i];
      qa[i*4+0] = t0.x; qa[i*4+1] = t0.y; qa[i*4+2] = t0.z; qa[i*4+3] = t0.w;
      qb[i*4+0] = t1.x; qb[i*4+1] = t1.y; qb[i*4+2] = t1.z; qb[i*4+3] = t1.w;
    }
    float sa[8], sb[8];
#pragma unroll
    for (int j = 0; j < 8; j++) {
      const float* kcol = KT + lane + 64 * j;
      float a0 = 0.f, a1 = 0.f;
#pragma unroll
      for (int d = 0; d < 32; d++) {
        float kv = kcol[d * 512];
        a0 += qa[d] * kv; a1 += qb[d] * kv;
      }
      sa[j] = a0 * scale; sb[j] = a1 * scale;
    }
    float m0 = sa[0], m1 = sb[0];
#pragma unroll
    for (int j = 1; j < 8; j++) { m0 = fmaxf(m0, sa[j]); m1 = fmaxf(m1, sb[j]); }
#pragma unroll
    for (int off = 32; off >= 1; off >>= 1) {
      m0 = fmaxf(m0, __shfl_xor(m0, off, 64));
      m1 = fmaxf(m1, __shfl_xor(m1, off, 64));
    }
    float s0 = 0.f, s1 = 0.f, pa[8], pb[8];
#pragma unroll
    for (int j = 0; j < 8; j++) {
      pa[j] = __expf(sa[j] - m0); s0 += pa[j];
      pb[j] = __expf(sb[j] - m1); s1 += pb[j];
    }
#pragma unroll
    for (int off = 32; off >= 1; off >>= 1) {
      s0 += __shfl_xor(s0, off, 64);
      s1 += __shfl_xor(s1, off, 64);
    }
    float inv0 = 1.f / s0, inv1 = 1.f / s1;
#pragma unroll
    for (int j = 0; j < 8; j++)
      pw[lane + 64 * j] = make_float2(pa[j] * inv0, pb[j] * inv1);
    int half = lane >> 5, d = lane & 31;
    float c0 = 0.f, c1 = 0.f;
    const float* vp = Vs + half * 256 * 32 + d;
    const float2* pp = pw + half * 256;
#pragma unroll 8
    for (int k = 0; k < 256; k++) {
      float vv = vp[k * 32];
      float2 p2 = pp[k];
      c0 += p2.x * vv; c1 += p2.y * vv;
    }
    c0 += __shfl_xor(c0, 32, 64);
    c1 += __shfl_xor(c1, 32, 64);
    if (lane < 32) {
      ctx[((size_t)(b * 512 + q0)) * 128 + h * 32 + d] = c0;
      ctx[((size_t)(b * 512 + q0 + 1)) * 128 + h * 32 + d] = c1;
    }
  }
}

// ---------------- residual add + LayerNorm (wave per row, E=128) ----------------
__global__ __launch_bounds__(256)
void add_ln_kernel(float* __restrict__ X, const float* __restrict__ Y,
                   const void* __restrict__ w, const void* __restrict__ bsh, size_t off,
                   const int* __restrict__ flag) {
  const int isbf = flag[0];
  int tid = threadIdx.x;
  int row = blockIdx.x * 4 + (tid >> 6);
  int lane = tid & 63;
  float2* xp = (float2*)(X + (size_t)row * 128);
  const float2* yp = (const float2*)(Y + (size_t)row * 128);
  float2 a = xp[lane], bb = yp[lane];
  float u0 = a.x + bb.x, u1 = a.y + bb.y;
  float s = u0 + u1, ss = u0 * u0 + u1 * u1;
#pragma unroll
  for (int off2 = 32; off2 >= 1; off2 >>= 1) {
    s += __shfl_xor(s, off2, 64);
    ss += __shfl_xor(ss, off2, 64);
  }
  float mean = s * (1.f / 128.f);
  float var = ss * (1.f / 128.f) - mean * mean;
  float rs = rsqrtf(var + 1e-5f);
  float o0 = (u0 - mean) * rs * rdw(w, off + lane * 2, isbf)     + rdw(bsh, off + lane * 2, isbf);
  float o1 = (u1 - mean) * rs * rdw(w, off + lane * 2 + 1, isbf) + rdw(bsh, off + lane * 2 + 1, isbf);
  xp[lane] = make_float2(o0, o1);
}

// ---------------- h0 = mean over S ----------------
__global__ __launch_bounds__(512)
void h0_kernel(const float* __restrict__ X, float* __restrict__ H0) {
  __shared__ float red[512];
  int b = blockIdx.x, tid = threadIdx.x;
  int e = tid & 127, q = tid >> 7;
  float s = 0.f;
  for (int s0 = q * 128; s0 < q * 128 + 128; s0++)
    s += X[((size_t)b * 512 + s0) * 128 + e];
  red[tid] = s;
  __syncthreads();
  if (q == 0)
    H0[b * 128 + e] = (red[e] + red[128 + e] + red[256 + e] + red[384 + e]) * (1.f / 512.f);
}

// ---------------- LSTM: one block per batch element, 63 steps ----------------
__global__ __launch_bounds__(512)
void lstm_kernel(const float* __restrict__ pre,  // [63,64,512] row=t*64+b (incl. b_ih+b_hh)
                 const float* __restrict__ h0,
                 const float* __restrict__ whh,  // [512,128] fp32
                 float* __restrict__ hall) {     // [63,64,128]
  __shared__ float hbuf[128];
  __shared__ float gates[512];
  int b = blockIdx.x, tid = threadIdx.x;
  float2 wreg[64];
  const float2* wrow = (const float2*)(whh + (size_t)tid * 128);
#pragma unroll
  for (int i = 0; i < 64; i++) wreg[i] = wrow[i];
  if (tid < 128) hbuf[tid] = h0[b * 128 + tid];
  float c = 0.f;
  __syncthreads();
  for (int t = 0; t < NSTEP; t++) {
    float acc0 = pre[((size_t)t * 64 + b) * 512 + tid];
    float acc1 = 0.f;
    const float2* h2 = (const float2*)hbuf;
#pragma unroll
    for (int i = 0; i < 64; i++) {
      float2 hh = h2[i];
      acc0 += wreg[i].x * hh.x;
      acc1 += wreg[i].y * hh.y;
    }
    gates[tid] = acc0 + acc1;
    __syncthreads();
    if (tid < 128) {
      float ig = gates[tid], fg = gates[128 + tid], gg = gates[256 + tid], og = gates[384 + tid];
      float si = 1.f / (1.f + __expf(-ig));
      float sf = 1.f / (1.f + __expf(-fg));
      float so = 1.f / (1.f + __expf(-og));
      c = sf * c + si * tanhf(gg);
      float hn = so * tanhf(c);
      hbuf[tid] = hn;
      hall[((size_t)t * 64 + b) * 128 + tid] = hn;
    }
    __syncthreads();
  }
}

// ---------------- launch ----------------
extern "C" void kernel_launch(void* const* d_in, const int* in_sizes, int n_in,
                              void* d_out, int out_size, void* d_ws, size_t ws_size,
                              hipStream_t stream) {
  const int* src     = (const int*)d_in[0];
  const int* trg     = (const int*)d_in[1];
  const void* emb_in  = d_in[2];
  const void* emb_out = d_in[3];
  const void* wqkv = d_in[4];
  const void* bqkv = d_in[5];
  const void* wo   = d_in[6];
  const void* bo   = d_in[7];
  const void* ln1w = d_in[8];
  const void* ln1b = d_in[9];
  const void* w1   = d_in[10];
  const void* b1   = d_in[11];
  const void* w2   = d_in[12];
  const void* b2   = d_in[13];
  const void* ln2w = d_in[14];
  const void* ln2b = d_in[15];
  const void* w_hh = d_in[17];
  const void* w_ih = d_in[16];
  const void* b_ih = d_in[18];
  const void* b_hh = d_in[19];
  const void* fc_w = d_in[20];
  const void* fc_b = d_in[21];

  float* ws   = (float*)d_ws;                       // ~101 MiB fp32 scratch
  float* X    = ws;                                 // [32768,128]
  float* BUF  = X + (size_t)32768 * 128;            // [32768,384]
  float* CTX1 = BUF + (size_t)32768 * 384;          // [32768,128]
  float* CTX2 = CTX1 + (size_t)32768 * 128;         // [32768,128]
  float* WHH  = CTX2 + (size_t)32768 * 128;         // [512,128]
  int*   FLAG = (int*)(WHH + 65536);
  // decoder-phase aliases inside BUF (BUF dead after layer-2 FF2)
  float* DEMB = BUF;                                // [4032,128]
  float* PRE  = BUF + 516096;                       // [4032,512]
  float* HALL = BUF + 2580480;                      // [63,64,128]
  float* H0   = BUF + 3096576;                      // [64,128]

  hipFuncSetAttribute((const void*)attn_kernel,
                      hipFuncAttributeMaxDynamicSharedMemorySize, 147456);

  detect_kernel<<<1, 64, 0, stream>>>(emb_in, FLAG);
  cvt_whh_kernel<<<256, 256, 0, stream>>>(w_hh, FLAG, WHH);
  embed_src_kernel<<<16384, 256, 0, stream>>>(src, emb_in, FLAG, X);
  for (int l = 0; l < 2; l++) {
    gemm_kernel<0><<<dim3(512, 6), 256, 0, stream>>>(
        X, wqkv, (size_t)l * 384 * 128, bqkv, (size_t)l * 384, nullptr, FLAG,
        BUF, nullptr, 32768, 384, 128);
    attn_kernel<<<256, 256, 147456, stream>>>(BUF, CTX1);
    gemm_kernel<0><<<dim3(512, 2), 256, 0, stream>>>(
        CTX1, wo, (size_t)l * 128 * 128, bo, (size_t)l * 128, nullptr, FLAG,
        CTX2, nullptr, 32768, 128, 128);
    add_ln_kernel<<<8192, 256, 0, stream>>>(X, CTX2, ln1w, ln1b, (size_t)l * 128, FLAG);
    gemm_kernel<1><<<dim3(512, 4), 256, 0, stream>>>(
        X, w1, (size_t)l * 256 * 128, b1, (size_t)l * 256, nullptr, FLAG,
        BUF, nullptr, 32768, 256, 128);
    gemm_kernel<0><<<dim3(512, 2), 256, 0, stream>>>(
        BUF, w2, (size_t)l * 128 * 256, b2, (size_t)l * 128, nullptr, FLAG,
        CTX2, nullptr, 32768, 128, 256);
    add_ln_kernel<<<8192, 256, 0, stream>>>(X, CTX2, ln2w, ln2b, (size_t)l * 128, FLAG);
  }
  h0_kernel<<<64, 512, 0, stream>>>(X, H0);
  embed_trg_kernel<<<2016, 256, 0, stream>>>(trg, emb_out, FLAG, DEMB);
  gemm_kernel<2><<<dim3(63, 8), 256, 0, stream>>>(
      DEMB, w_ih, 0, b_ih, 0, b_hh, FLAG, PRE, nullptr, 4032, 512, 128);
  lstm_kernel<<<64, 512, 0, stream>>>(PRE, H0, WHH, HALL);
  gemm_kernel<4><<<dim3(63, 500), 256, 0, stream>>>(
      HALL, fc_w, 0, fc_b, 0, nullptr, FLAG, nullptr, d_out, 4032, VOUT_N, 128);
}